// Round 1
// baseline (2002.164 us; speedup 1.0000x reference)
//
#include <hip/hip_runtime.h>

#define DEV __device__ __forceinline__

// ---------------------------------------------------------------------------
// B-spline machinery: GRID_SIZE=5, DEGREE=3, knots t_i = (i-3)*0.4 - 1, i=0..11
// Cox-de Boor exactly as the reference (half-open order-0 intervals).
// ---------------------------------------------------------------------------
DEV float silu_f(float v) { return v / (1.0f + __expf(-v)); }

DEV void bspline11(float x, float b[11], int& m_out) {
    int m = -1;
#pragma unroll
    for (int i = 0; i < 11; ++i) {
        float g0 = (i - 3) * 0.4f - 1.0f;
        float g1 = (i - 2) * 0.4f - 1.0f;
        bool c = (x >= g0) && (x < g1);
        b[i] = c ? 1.0f : 0.0f;
        if (c) m = i;
    }
#pragma unroll
    for (int d = 1; d <= 3; ++d) {
        const float inv = 1.0f / (0.4f * (float)d);
#pragma unroll
        for (int i = 0; i < 11 - d; ++i) {
            float gl = (i - 3) * 0.4f - 1.0f;
            float gr = (i - 3 + d + 1) * 0.4f - 1.0f;
            b[i] = (x - gl) * inv * b[i] + (gr - x) * inv * b[i + 1];
        }
    }
    m_out = m;
}

// ---------------------------------------------------------------------------
// KANConv (k=3, pad=1) + 2x2/2 maxpool. One block per sample.
//   in  : [B, CIN, H, W]
//   wb  : [O, CIN*9]
//   ws  : [O, CIN*9, 8]
//   outp: [B, O, PH, PH]
// G = output-channel group per work item.
// ---------------------------------------------------------------------------
template <int CIN, int H, int W, int O, int G, int PH>
__global__ __launch_bounds__(256) void kan_conv3(
    const float* __restrict__ in, const float* __restrict__ wb,
    const float* __restrict__ ws, float* __restrict__ outp) {
    constexpr int NPIX = H * W;
    constexpr int NIN = CIN * NPIX;
    constexpr int F = CIN * 9;

    __shared__ float s_sil[NIN];
    __shared__ float s_bs4[NIN * 4];
    __shared__ int s_js[NIN];
    __shared__ float s_wb[O * F];
    __shared__ float s_ws[O * F * 8];
    __shared__ float s_out[O * NPIX];

    const int b = blockIdx.x;
    const int tid = threadIdx.x;

    for (int i = tid; i < O * F; i += 256) s_wb[i] = wb[i];
    for (int i = tid; i < O * F * 8; i += 256) s_ws[i] = ws[i];

    // Expansion: silu + 4-nonzero spline bases per input value.
    const float* xin = in + (size_t)b * NIN;
    for (int i = tid; i < NIN; i += 256) {
        float v = xin[i];
        s_sil[i] = silu_f(v);
        float bb[11];
        int m;
        bspline11(v, bb, m);
        int js = min(max(m - 3, 0), 4);  // m=-1 (out of grid) -> 0, bases all 0
        s_js[i] = js;
#pragma unroll
        for (int r = 0; r < 4; ++r) s_bs4[i * 4 + r] = bb[js + r];
    }

    // Zero-pad contribution constants (B_j(0) != 0 !). Constant-foldable.
    float zbb[11];
    int zm;
    bspline11(0.0f, zbb, zm);
    const int zjs = min(max(zm - 3, 0), 4);
    const float zb0 = zbb[zjs], zb1 = zbb[zjs + 1], zb2 = zbb[zjs + 2], zb3 = zbb[zjs + 3];

    __syncthreads();

    // Conv: item = (pixel, output-group of G channels)
    constexpr int NOG = O / G;
    constexpr int NITEM = NPIX * NOG;
    for (int it = tid; it < NITEM; it += 256) {
        int px = it % NPIX;
        int og = it / NPIX;
        int y = px / W, x = px % W;
        float acc[G];
#pragma unroll
        for (int g = 0; g < G; ++g) acc[g] = 0.0f;
#pragma unroll
        for (int dy = 0; dy < 3; ++dy) {
            int iy = y + dy - 1;
#pragma unroll
            for (int dx = 0; dx < 3; ++dx) {
                int ix = x + dx - 1;
                bool inb = ((unsigned)iy < (unsigned)H) && ((unsigned)ix < (unsigned)W);
                for (int c = 0; c < CIN; ++c) {
                    int f = c * 9 + dy * 3 + dx;
                    float s, b0, b1, b2, b3;
                    int js;
                    if (inb) {
                        int idx = c * NPIX + iy * W + ix;
                        s = s_sil[idx];
                        js = s_js[idx];
                        b0 = s_bs4[idx * 4 + 0];
                        b1 = s_bs4[idx * 4 + 1];
                        b2 = s_bs4[idx * 4 + 2];
                        b3 = s_bs4[idx * 4 + 3];
                    } else {
                        s = 0.0f;
                        js = zjs;
                        b0 = zb0; b1 = zb1; b2 = zb2; b3 = zb3;
                    }
#pragma unroll
                    for (int g = 0; g < G; ++g) {
                        int o = og * G + g;
                        const float* wr = &s_ws[(o * F + f) * 8 + js];
                        acc[g] += s_wb[o * F + f] * s + wr[0] * b0 + wr[1] * b1 +
                                  wr[2] * b2 + wr[3] * b3;
                    }
                }
            }
        }
#pragma unroll
        for (int g = 0; g < G; ++g) s_out[(og * G + g) * NPIX + px] = acc[g];
    }
    __syncthreads();

    // 2x2 stride-2 VALID maxpool
    constexpr int NPOOL = O * PH * PH;
    float* op = outp + (size_t)b * NPOOL;
    for (int i = tid; i < NPOOL; i += 256) {
        int o = i / (PH * PH);
        int r = i % (PH * PH);
        int py = r / PH, px = r % PH;
        const float* src = &s_out[o * NPIX + (2 * py) * W + 2 * px];
        float m0 = fmaxf(src[0], src[1]);
        float m1 = fmaxf(src[W], src[W + 1]);
        op[i] = fmaxf(m0, m1);
    }
}

// ---------------------------------------------------------------------------
// Layer-4 weight pre-reduction (sample independent, single tiny launch).
// For k=2,pad=1 on 3x3 input, every f=(c,dy,dx) touches all 9 valid pixels of
// channel c exactly once plus 7 zero-pads. Global-mean commutes with the
// linear maps, so:
//   pooled[o] = (1/16)[ Σ_c Wb̄[o,c]·SilSum[c] + Σ_{c,j} Ws̄[o,c,j]·BsSum[c,j]
//                       + 7·Σ_{f,j} ws[o,f,j]·B_j(0) ]
// wr layout: [0,512) Wb̄[32][16]; [512,4608) Ws̄[32][16][8]; [4608,4640) beta7
// ---------------------------------------------------------------------------
__global__ __launch_bounds__(256) void kan4_reduce(const float* __restrict__ wb4,
                                                   const float* __restrict__ ws4,
                                                   float* __restrict__ wr) {
    const int tid = threadIdx.x;
    for (int i = tid; i < 32 * 16; i += 256) {
        int o = i / 16, c = i % 16;
        float s = 0.0f;
        for (int q = 0; q < 4; ++q) s += wb4[o * 64 + c * 4 + q];
        wr[i] = s;
    }
    for (int i = tid; i < 32 * 16 * 8; i += 256) {
        int j = i % 8, c = (i / 8) % 16, o = i / 128;
        float s = 0.0f;
        for (int q = 0; q < 4; ++q) s += ws4[(o * 64 + c * 4 + q) * 8 + j];
        wr[512 + i] = s;
    }
    float zbb[11];
    int zm;
    bspline11(0.0f, zbb, zm);
    for (int o = tid; o < 32; o += 256) {
        float s = 0.0f;
        for (int f = 0; f < 64; ++f)
            for (int j = 0; j < 8; ++j) s += ws4[(o * 64 + f) * 8 + j] * zbb[j];
        wr[512 + 4096 + o] = 7.0f * s;
    }
}

// ---------------------------------------------------------------------------
// Layer 4 + global-avg + fc, one block per sample.
//   in: [B,16,3,3]  out: [B,10]
// ---------------------------------------------------------------------------
__global__ __launch_bounds__(256) void kan4_tail(const float* __restrict__ in,
                                                 const float* __restrict__ wr,
                                                 const float* __restrict__ fcw,
                                                 const float* __restrict__ fcb,
                                                 float* __restrict__ out) {
    __shared__ float s_sil[144];
    __shared__ float s_bs[144 * 8];
    __shared__ float s_cs[16 * 9];  // [c][0]=silu sum, [c][1+j]=basis-j sum
    __shared__ float s_pool[32];
    const int b = blockIdx.x;
    const int tid = threadIdx.x;
    const float* xin = in + (size_t)b * 144;
    if (tid < 144) {
        float v = xin[tid];
        s_sil[tid] = silu_f(v);
        float bb[11];
        int m;
        bspline11(v, bb, m);
#pragma unroll
        for (int j = 0; j < 8; ++j) s_bs[tid * 8 + j] = bb[j];
    }
    __syncthreads();
    if (tid < 144) {  // 16 channels x 9 components
        int c = tid / 9, comp = tid % 9;
        float s = 0.0f;
        for (int p = 0; p < 9; ++p) {
            int idx = c * 9 + p;
            s += (comp == 0) ? s_sil[idx] : s_bs[idx * 8 + (comp - 1)];
        }
        s_cs[tid] = s;
    }
    __syncthreads();
    if (tid < 32) {
        int o = tid;
        float acc = wr[512 + 4096 + o];  // 7 * sum(ws * B(0))
        for (int c = 0; c < 16; ++c) {
            acc += wr[o * 16 + c] * s_cs[c * 9 + 0];
            for (int j = 0; j < 8; ++j)
                acc += wr[512 + (o * 16 + c) * 8 + j] * s_cs[c * 9 + 1 + j];
        }
        s_pool[o] = acc * (1.0f / 16.0f);
    }
    __syncthreads();
    if (tid < 10) {
        float acc = fcb[tid];
        for (int c = 0; c < 32; ++c) acc += fcw[tid * 32 + c] * s_pool[c];
        out[b * 10 + tid] = acc;
    }
}

// ---------------------------------------------------------------------------
extern "C" void kernel_launch(void* const* d_in, const int* in_sizes, int n_in,
                              void* d_out, int out_size, void* d_ws, size_t ws_size,
                              hipStream_t stream) {
    const float* x = (const float*)d_in[0];      // [B,1,28,28]
    const float* wb1 = (const float*)d_in[1];    // [4,9]
    const float* ws1 = (const float*)d_in[2];    // [4,9,8]
    const float* wb2 = (const float*)d_in[3];    // [8,36]
    const float* ws2 = (const float*)d_in[4];    // [8,36,8]
    const float* wb3 = (const float*)d_in[5];    // [16,72]
    const float* ws3 = (const float*)d_in[6];    // [16,72,8]
    const float* wb4 = (const float*)d_in[7];    // [32,64]
    const float* ws4 = (const float*)d_in[8];    // [32,64,8]
    const float* fcw = (const float*)d_in[9];    // [10,32]
    const float* fcb = (const float*)d_in[10];   // [10]
    float* out = (float*)d_out;

    const int B = in_sizes[0] / (28 * 28);

    float* p1 = (float*)d_ws;              // [B,4,14,14]
    float* p2 = p1 + (size_t)B * 4 * 14 * 14;  // [B,8,7,7]
    float* p3 = p2 + (size_t)B * 8 * 7 * 7;    // [B,16,3,3]
    float* wr = p3 + (size_t)B * 16 * 9;       // 4640 floats

    kan4_reduce<<<1, 256, 0, stream>>>(wb4, ws4, wr);
    kan_conv3<1, 28, 28, 4, 4, 14><<<B, 256, 0, stream>>>(x, wb1, ws1, p1);
    kan_conv3<4, 14, 14, 8, 4, 7><<<B, 256, 0, stream>>>(p1, wb2, ws2, p2);
    kan_conv3<8, 7, 7, 16, 2, 3><<<B, 256, 0, stream>>>(p2, wb3, ws3, p3);
    kan4_tail<<<B, 256, 0, stream>>>(p3, wr, fcw, fcb, out);
}

// Round 2
// 339.233 us; speedup vs baseline: 5.9020x; 5.9020x over previous
//
#include <hip/hip_runtime.h>

#define DEV __device__ __forceinline__

// ---------------------------------------------------------------------------
// B-spline machinery: GRID_SIZE=5, DEGREE=3, knots t_i = (i-3)*0.4 - 1.
// Cox-de Boor exactly as the reference. Returns all 8 degree-3 bases.
// No runtime-indexed private arrays (everything fully unrolled, const idx).
// ---------------------------------------------------------------------------
DEV float silu_f(float v) { return v / (1.0f + __expf(-v)); }

DEV void bspline8(float x, float bb[8]) {
    float b[11];
#pragma unroll
    for (int i = 0; i < 11; ++i) {
        float g0 = (i - 3) * 0.4f - 1.0f;
        float g1 = (i - 2) * 0.4f - 1.0f;
        b[i] = ((x >= g0) && (x < g1)) ? 1.0f : 0.0f;
    }
#pragma unroll
    for (int d = 1; d <= 3; ++d) {
        const float inv = 1.0f / (0.4f * (float)d);
#pragma unroll
        for (int i = 0; i < 11 - d; ++i) {
            float gl = (i - 3) * 0.4f - 1.0f;
            float gr = (i - 3 + d + 1) * 0.4f - 1.0f;
            b[i] = (x - gl) * inv * b[i] + (gr - x) * inv * b[i + 1];
        }
    }
#pragma unroll
    for (int j = 0; j < 8; ++j) bb[j] = b[j];
}

// ---------------------------------------------------------------------------
// Expansion: silu + 8 bases per input element, planar LDS layout.
// Element NE is the zero-pad element: sil=0, bases=B(0).
// ---------------------------------------------------------------------------
DEV void expand_feat(const float* __restrict__ src, int NE, float* s_sil,
                     float4* s_bsA, float4* s_bsB, int tid) {
    for (int i = tid; i <= NE; i += 256) {
        float v = (i == NE) ? 0.0f : src[i];
        s_sil[i] = (i == NE) ? 0.0f : silu_f(v);
        float bb[8];
        bspline8(v, bb);
        s_bsA[i] = make_float4(bb[0], bb[1], bb[2], bb[3]);
        s_bsB[i] = make_float4(bb[4], bb[5], bb[6], bb[7]);
    }
}

// ---------------------------------------------------------------------------
// KANConv (k=3, pad=1) phase. Feat from LDS (vector), weights from GLOBAL
// with wave-uniform indices -> compiler emits s_load (SGPR operands).
// Each wave owns output-channel group og = wave_id % NOG (readfirstlane'd
// so the compiler can prove uniformity).
// ---------------------------------------------------------------------------
template <int CIN, int H, int W, int O, int G>
DEV void conv_phase(const float* __restrict__ wb, const float* __restrict__ ws,
                    const float* s_sil, const float4* s_bsA, const float4* s_bsB,
                    float* s_out, int tid) {
    constexpr int NPIX = H * W;
    constexpr int F = CIN * 9;
    constexpr int NOG = O / G;
    constexpr int NIN = CIN * NPIX;
    static_assert(4 % NOG == 0, "waves must cover groups");

    const int wv = __builtin_amdgcn_readfirstlane(tid >> 6);
    const int ln = tid & 63;
    const int og = wv % NOG;              // uniform per wave
    const int pxoff = (wv / NOG) * 64;    // uniform per wave
    constexpr int PXSTRIDE = 64 * (4 / NOG);

    for (int px = ln + pxoff; px < NPIX; px += PXSTRIDE) {
        const int y = px / W, x = px - y * W;
        int nbr[9];
#pragma unroll
        for (int t = 0; t < 9; ++t) {
            int iy = y + (t / 3) - 1;
            int ix = x + (t % 3) - 1;
            bool v = ((unsigned)iy < (unsigned)H) && ((unsigned)ix < (unsigned)W);
            nbr[t] = v ? iy * W + ix : -1;
        }
        float acc[G];
#pragma unroll
        for (int g = 0; g < G; ++g) acc[g] = 0.0f;

#pragma unroll 1
        for (int c = 0; c < CIN; ++c) {
#pragma unroll
            for (int t = 0; t < 9; ++t) {
                const int idx = (nbr[t] < 0) ? NIN : c * NPIX + nbr[t];
                const float s = s_sil[idx];
                const float4 a = s_bsA[idx];
                const float4 bqu = s_bsB[idx];
                const int f = c * 9 + t;
#pragma unroll
                for (int g = 0; g < G; ++g) {
                    const int o = og * G + g;              // uniform
                    const float* w8 = ws + (o * F + f) * 8;  // uniform -> s_load
                    float ag = acc[g];
                    ag = fmaf(wb[o * F + f], s, ag);
                    ag = fmaf(w8[0], a.x, ag);
                    ag = fmaf(w8[1], a.y, ag);
                    ag = fmaf(w8[2], a.z, ag);
                    ag = fmaf(w8[3], a.w, ag);
                    ag = fmaf(w8[4], bqu.x, ag);
                    ag = fmaf(w8[5], bqu.y, ag);
                    ag = fmaf(w8[6], bqu.z, ag);
                    ag = fmaf(w8[7], bqu.w, ag);
                    acc[g] = ag;
                }
            }
        }
#pragma unroll
        for (int g = 0; g < G; ++g) s_out[(og * G + g) * NPIX + px] = acc[g];
    }
}

// 2x2 stride-2 VALID maxpool: s_out [O][H][W] -> dst [O][PH][PH]
template <int O, int H, int W, int PH>
DEV void pool_phase(const float* s_out, float* dst, int tid) {
    constexpr int NPIX = H * W;
    constexpr int NPOOL = O * PH * PH;
    for (int i = tid; i < NPOOL; i += 256) {
        int o = i / (PH * PH);
        int r = i - o * (PH * PH);
        int py = r / PH, px = r - py * PH;
        const float* src = &s_out[o * NPIX + (2 * py) * W + 2 * px];
        dst[i] = fmaxf(fmaxf(src[0], src[1]), fmaxf(src[W], src[W + 1]));
    }
}

// ---------------------------------------------------------------------------
// Layer-4 weight pre-reduction (sample independent, one tiny launch).
// wr layout: [0,512) Wb~[32][16]; [512,4608) Ws~[32][16][8]; [4608,4640) beta7
// ---------------------------------------------------------------------------
__global__ __launch_bounds__(256) void kan4_reduce(const float* __restrict__ wb4,
                                                   const float* __restrict__ ws4,
                                                   float* __restrict__ wr) {
    const int tid = threadIdx.x;
    for (int i = tid; i < 32 * 16; i += 256) {
        int o = i / 16, c = i % 16;
        float s = 0.0f;
        for (int q = 0; q < 4; ++q) s += wb4[o * 64 + c * 4 + q];
        wr[i] = s;
    }
    for (int i = tid; i < 32 * 16 * 8; i += 256) {
        int j = i % 8, c = (i / 8) % 16, o = i / 128;
        float s = 0.0f;
        for (int q = 0; q < 4; ++q) s += ws4[(o * 64 + c * 4 + q) * 8 + j];
        wr[512 + i] = s;
    }
    float zbb[8];
    bspline8(0.0f, zbb);
    for (int o = tid; o < 32; o += 256) {
        float s = 0.0f;
        for (int f = 0; f < 64; ++f)
#pragma unroll
            for (int j = 0; j < 8; ++j) s += ws4[(o * 64 + f) * 8 + j] * zbb[j];
        wr[512 + 4096 + o] = 7.0f * s;
    }
}

// ---------------------------------------------------------------------------
// Fully fused network: one block per sample. All intermediates live in LDS.
// ---------------------------------------------------------------------------
__global__ __launch_bounds__(256) void kan_fused(
    const float* __restrict__ x,
    const float* __restrict__ wb1, const float* __restrict__ ws1,
    const float* __restrict__ wb2, const float* __restrict__ ws2,
    const float* __restrict__ wb3, const float* __restrict__ ws3,
    const float* __restrict__ wr, const float* __restrict__ fcw,
    const float* __restrict__ fcb, float* __restrict__ out) {
    __shared__ float s_sil[786];
    __shared__ float4 s_bsA[786];
    __shared__ float4 s_bsB[786];
    __shared__ float s_out[3136];
    __shared__ float s_p[784];
    __shared__ float s_cs[144];
    __shared__ float s_pool[32];

    const int b = blockIdx.x;
    const int tid = threadIdx.x;

    // stage input image
    for (int i = tid; i < 784; i += 256) s_p[i] = x[(size_t)b * 784 + i];
    __syncthreads();

    // ----- layer 1: [1,28,28] -> [4,28,28] -> pool [4,14,14]
    expand_feat(s_p, 784, s_sil, s_bsA, s_bsB, tid);
    __syncthreads();
    conv_phase<1, 28, 28, 4, 4>(wb1, ws1, s_sil, s_bsA, s_bsB, s_out, tid);
    __syncthreads();
    pool_phase<4, 28, 28, 14>(s_out, s_p, tid);
    __syncthreads();

    // ----- layer 2: [4,14,14] -> [8,14,14] -> pool [8,7,7]
    expand_feat(s_p, 784, s_sil, s_bsA, s_bsB, tid);
    __syncthreads();
    conv_phase<4, 14, 14, 8, 4>(wb2, ws2, s_sil, s_bsA, s_bsB, s_out, tid);
    __syncthreads();
    pool_phase<8, 14, 14, 7>(s_out, s_p, tid);
    __syncthreads();

    // ----- layer 3: [8,7,7] -> [16,7,7] -> pool [16,3,3]
    expand_feat(s_p, 392, s_sil, s_bsA, s_bsB, tid);
    __syncthreads();
    conv_phase<8, 7, 7, 16, 4>(wb3, ws3, s_sil, s_bsA, s_bsB, s_out, tid);
    __syncthreads();
    pool_phase<16, 7, 7, 3>(s_out, s_p, tid);
    __syncthreads();

    // ----- layer 4 + global-avg + fc (algebraically collapsed via wr)
    if (tid < 144) {
        float v = s_p[tid];
        s_sil[tid] = silu_f(v);
        float bb[8];
        bspline8(v, bb);
        s_bsA[tid] = make_float4(bb[0], bb[1], bb[2], bb[3]);
        s_bsB[tid] = make_float4(bb[4], bb[5], bb[6], bb[7]);
    }
    __syncthreads();
    if (tid < 144) {  // 16 channels x 9 components (silu, 8 bases)
        int c = tid / 9, comp = tid % 9;
        float s = 0.0f;
        for (int p = 0; p < 9; ++p) {
            int idx = c * 9 + p;
            float val;
            if (comp == 0) {
                val = s_sil[idx];
            } else {
                int j = comp - 1;
                val = (j < 4) ? ((const float*)&s_bsA[idx])[j]
                              : ((const float*)&s_bsB[idx])[j - 4];
            }
            s += val;
        }
        s_cs[tid] = s;
    }
    __syncthreads();
    if (tid < 32) {
        int o = tid;
        float acc = wr[4608 + o];  // 7 * sum(ws4 * B(0))
        for (int c = 0; c < 16; ++c) {
            acc += wr[o * 16 + c] * s_cs[c * 9 + 0];
#pragma unroll
            for (int j = 0; j < 8; ++j)
                acc += wr[512 + (o * 16 + c) * 8 + j] * s_cs[c * 9 + 1 + j];
        }
        s_pool[o] = acc * (1.0f / 16.0f);
    }
    __syncthreads();
    if (tid < 10) {
        float acc = fcb[tid];
#pragma unroll
        for (int c = 0; c < 32; ++c) acc += fcw[tid * 32 + c] * s_pool[c];
        out[(size_t)b * 10 + tid] = acc;
    }
}

// ---------------------------------------------------------------------------
extern "C" void kernel_launch(void* const* d_in, const int* in_sizes, int n_in,
                              void* d_out, int out_size, void* d_ws, size_t ws_size,
                              hipStream_t stream) {
    const float* x = (const float*)d_in[0];      // [B,1,28,28]
    const float* wb1 = (const float*)d_in[1];    // [4,9]
    const float* ws1 = (const float*)d_in[2];    // [4,9,8]
    const float* wb2 = (const float*)d_in[3];    // [8,36]
    const float* ws2 = (const float*)d_in[4];    // [8,36,8]
    const float* wb3 = (const float*)d_in[5];    // [16,72]
    const float* ws3 = (const float*)d_in[6];    // [16,72,8]
    const float* wb4 = (const float*)d_in[7];    // [32,64]
    const float* ws4 = (const float*)d_in[8];    // [32,64,8]
    const float* fcw = (const float*)d_in[9];    // [10,32]
    const float* fcb = (const float*)d_in[10];   // [10]
    float* out = (float*)d_out;

    const int B = in_sizes[0] / (28 * 28);
    float* wr = (float*)d_ws;  // 4640 floats

    kan4_reduce<<<1, 256, 0, stream>>>(wb4, ws4, wr);
    kan_fused<<<B, 256, 0, stream>>>(x, wb1, ws1, wb2, ws2, wb3, ws3, wr, fcw,
                                     fcb, out);
}

// Round 3
// 228.318 us; speedup vs baseline: 8.7692x; 1.4858x over previous
//
#include <hip/hip_runtime.h>

#define DEV __device__ __forceinline__

// ---------------------------------------------------------------------------
// B-spline machinery: GRID_SIZE=5, DEGREE=3, knots t_i = (i-3)*0.4 - 1.
// Cox-de Boor exactly as the reference. All-unrolled, no runtime indexing.
// ---------------------------------------------------------------------------
DEV float silu_f(float v) { return v / (1.0f + __expf(-v)); }

DEV void bspline8(float x, float bb[8]) {
    float b[11];
#pragma unroll
    for (int i = 0; i < 11; ++i) {
        float g0 = (i - 3) * 0.4f - 1.0f;
        float g1 = (i - 2) * 0.4f - 1.0f;
        b[i] = ((x >= g0) && (x < g1)) ? 1.0f : 0.0f;
    }
#pragma unroll
    for (int d = 1; d <= 3; ++d) {
        const float inv = 1.0f / (0.4f * (float)d);
#pragma unroll
        for (int i = 0; i < 11 - d; ++i) {
            float gl = (i - 3) * 0.4f - 1.0f;
            float gr = (i - 3 + d + 1) * 0.4f - 1.0f;
            b[i] = (x - gl) * inv * b[i] + (gr - x) * inv * b[i + 1];
        }
    }
#pragma unroll
    for (int j = 0; j < 8; ++j) bb[j] = b[j];
}

// XOR swizzle for the float4 basis arrays: breaks the 16-way bank conflict of
// stride-2-pixel (32B) ds_read_b128 gathers while keeping contiguous access
// conflict-free (within-row permutation only).
DEV int swz(int i) { return i ^ ((i >> 3) & 7); }

// ---------------------------------------------------------------------------
// Expansion: silu + 8 bases per input element, planar LDS. Element NE is the
// zero-pad element: sil=0, bases=B(0).
// ---------------------------------------------------------------------------
DEV void expand_feat(const float* src, int NE, float* s_sil, float4* s_bsA,
                     float4* s_bsB, int tid) {
    for (int i = tid; i <= NE; i += 256) {
        float v = (i == NE) ? 0.0f : src[i];
        s_sil[i] = (i == NE) ? 0.0f : silu_f(v);
        float bb[8];
        bspline8(v, bb);
        s_bsA[swz(i)] = make_float4(bb[0], bb[1], bb[2], bb[3]);
        s_bsB[swz(i)] = make_float4(bb[4], bb[5], bb[6], bb[7]);
    }
}

// ---------------------------------------------------------------------------
// Fused KANConv (k=3,pad=1) + 2x2/2 maxpool, pool done in registers.
// Each lane owns a 2x2 output patch for G channels; the 4x4 input-support
// positions are loaded once each and scattered into the 4 accumulators.
// Weights from global with wave-uniform indices -> s_load (SGPR operands).
// ---------------------------------------------------------------------------
template <int CIN, int H, int W, int O, int G>
DEV void conv_pool_phase(const float* __restrict__ wb, const float* __restrict__ ws,
                         const float* s_sil, const float4* s_bsA,
                         const float4* s_bsB, float* dst, int tid) {
    constexpr int PH = H / 2;
    constexpr int NPATCH = PH * PH;
    constexpr int NPIX = H * W;
    constexpr int NIN = CIN * NPIX;
    constexpr int F = CIN * 9;
    constexpr int NOG = O / G;
    static_assert(4 % NOG == 0, "waves must cover groups");

    const int wv = __builtin_amdgcn_readfirstlane(tid >> 6);
    const int ln = tid & 63;
    const int og = wv % NOG;            // uniform per wave
    const int poff = (wv / NOG) * 64;   // uniform per wave
    constexpr int PSTRIDE = 64 * (4 / NOG);

    for (int p = ln + poff; p < NPATCH; p += PSTRIDE) {
        const int py = p / PH, px = p - py * PH;
        int nbr[16];
#pragma unroll
        for (int u = 0; u < 4; ++u)
#pragma unroll
            for (int v = 0; v < 4; ++v) {
                int iy = 2 * py + u - 1;
                int ix = 2 * px + v - 1;
                bool inb = ((unsigned)iy < (unsigned)H) && ((unsigned)ix < (unsigned)W);
                nbr[u * 4 + v] = inb ? iy * W + ix : -1;
            }
        float acc[G][4];
#pragma unroll
        for (int g = 0; g < G; ++g)
#pragma unroll
            for (int q = 0; q < 4; ++q) acc[g][q] = 0.0f;

#pragma unroll 1
        for (int c = 0; c < CIN; ++c) {
#pragma unroll
            for (int u = 0; u < 4; ++u) {
#pragma unroll
                for (int v = 0; v < 4; ++v) {
                    const int nb = nbr[u * 4 + v];
                    const int idx = (nb < 0) ? NIN : c * NPIX + nb;
                    const int sx = swz(idx);
                    const float s = s_sil[idx];
                    const float4 a = s_bsA[sx];
                    const float4 bq = s_bsB[sx];
#pragma unroll
                    for (int oy = 0; oy < 2; ++oy) {
                        const int dy = u - oy;  // tap row
                        if (dy < 0 || dy > 2) continue;
#pragma unroll
                        for (int ox = 0; ox < 2; ++ox) {
                            const int dx = v - ox;
                            if (dx < 0 || dx > 2) continue;
                            const int f = c * 9 + dy * 3 + dx;
#pragma unroll
                            for (int g = 0; g < G; ++g) {
                                const int o = og * G + g;                 // uniform
                                const float* w8 = ws + (o * F + f) * 8;   // -> s_load
                                float ag = acc[g][oy * 2 + ox];
                                ag = fmaf(wb[o * F + f], s, ag);
                                ag = fmaf(w8[0], a.x, ag);
                                ag = fmaf(w8[1], a.y, ag);
                                ag = fmaf(w8[2], a.z, ag);
                                ag = fmaf(w8[3], a.w, ag);
                                ag = fmaf(w8[4], bq.x, ag);
                                ag = fmaf(w8[5], bq.y, ag);
                                ag = fmaf(w8[6], bq.z, ag);
                                ag = fmaf(w8[7], bq.w, ag);
                                acc[g][oy * 2 + ox] = ag;
                            }
                        }
                    }
                }
            }
        }
#pragma unroll
        for (int g = 0; g < G; ++g) {
            float m = fmaxf(fmaxf(acc[g][0], acc[g][1]), fmaxf(acc[g][2], acc[g][3]));
            dst[(og * G + g) * NPATCH + p] = m;
        }
    }
}

// ---------------------------------------------------------------------------
// Pixel-wise KANConv (for the odd 7x7 layer), writes conv output to s_out.
// ---------------------------------------------------------------------------
template <int CIN, int H, int W, int O, int G>
DEV void conv_phase(const float* __restrict__ wb, const float* __restrict__ ws,
                    const float* s_sil, const float4* s_bsA, const float4* s_bsB,
                    float* s_out, int tid) {
    constexpr int NPIX = H * W;
    constexpr int F = CIN * 9;
    constexpr int NOG = O / G;
    constexpr int NIN = CIN * NPIX;
    static_assert(4 % NOG == 0, "waves must cover groups");

    const int wv = __builtin_amdgcn_readfirstlane(tid >> 6);
    const int ln = tid & 63;
    const int og = wv % NOG;
    const int pxoff = (wv / NOG) * 64;
    constexpr int PXSTRIDE = 64 * (4 / NOG);

    for (int px = ln + pxoff; px < NPIX; px += PXSTRIDE) {
        const int y = px / W, x = px - y * W;
        int nbr[9];
#pragma unroll
        for (int t = 0; t < 9; ++t) {
            int iy = y + (t / 3) - 1;
            int ix = x + (t % 3) - 1;
            bool v = ((unsigned)iy < (unsigned)H) && ((unsigned)ix < (unsigned)W);
            nbr[t] = v ? iy * W + ix : -1;
        }
        float acc[G];
#pragma unroll
        for (int g = 0; g < G; ++g) acc[g] = 0.0f;

#pragma unroll 1
        for (int c = 0; c < CIN; ++c) {
#pragma unroll
            for (int t = 0; t < 9; ++t) {
                const int idx = (nbr[t] < 0) ? NIN : c * NPIX + nbr[t];
                const int sx = swz(idx);
                const float s = s_sil[idx];
                const float4 a = s_bsA[sx];
                const float4 bq = s_bsB[sx];
                const int f = c * 9 + t;
#pragma unroll
                for (int g = 0; g < G; ++g) {
                    const int o = og * G + g;
                    const float* w8 = ws + (o * F + f) * 8;
                    float ag = acc[g];
                    ag = fmaf(wb[o * F + f], s, ag);
                    ag = fmaf(w8[0], a.x, ag);
                    ag = fmaf(w8[1], a.y, ag);
                    ag = fmaf(w8[2], a.z, ag);
                    ag = fmaf(w8[3], a.w, ag);
                    ag = fmaf(w8[4], bq.x, ag);
                    ag = fmaf(w8[5], bq.y, ag);
                    ag = fmaf(w8[6], bq.z, ag);
                    ag = fmaf(w8[7], bq.w, ag);
                    acc[g] = ag;
                }
            }
        }
#pragma unroll
        for (int g = 0; g < G; ++g) s_out[(og * G + g) * NPIX + px] = acc[g];
    }
}

// ---------------------------------------------------------------------------
// Layer-4 weight pre-reduction (sample independent, one tiny launch).
// wr layout: [0,512) Wb~[32][16]; [512,4608) Ws~[32][16][8]; [4608,4640) beta7
// ---------------------------------------------------------------------------
__global__ __launch_bounds__(256) void kan4_reduce(const float* __restrict__ wb4,
                                                   const float* __restrict__ ws4,
                                                   float* __restrict__ wr) {
    const int tid = threadIdx.x;
    for (int i = tid; i < 32 * 16; i += 256) {
        int o = i / 16, c = i % 16;
        float s = 0.0f;
        for (int q = 0; q < 4; ++q) s += wb4[o * 64 + c * 4 + q];
        wr[i] = s;
    }
    for (int i = tid; i < 32 * 16 * 8; i += 256) {
        int j = i % 8, c = (i / 8) % 16, o = i / 128;
        float s = 0.0f;
        for (int q = 0; q < 4; ++q) s += ws4[(o * 64 + c * 4 + q) * 8 + j];
        wr[512 + i] = s;
    }
    float zbb[8];
    bspline8(0.0f, zbb);
    for (int o = tid; o < 32; o += 256) {
        float s = 0.0f;
        for (int f = 0; f < 64; ++f)
#pragma unroll
            for (int j = 0; j < 8; ++j) s += ws4[(o * 64 + f) * 8 + j] * zbb[j];
        wr[512 + 4096 + o] = 7.0f * s;
    }
}

// ---------------------------------------------------------------------------
// Fully fused network: one block per sample, ~31.6 KB LDS -> 5 blocks/CU.
// ---------------------------------------------------------------------------
__global__ __launch_bounds__(256, 5) void kan_fused(
    const float* __restrict__ x,
    const float* __restrict__ wb1, const float* __restrict__ ws1,
    const float* __restrict__ wb2, const float* __restrict__ ws2,
    const float* __restrict__ wb3, const float* __restrict__ ws3,
    const float* __restrict__ wr, const float* __restrict__ fcw,
    const float* __restrict__ fcb, float* __restrict__ out) {
    __shared__ float s_sil[785];
    __shared__ float4 s_bsA[792];   // swizzled indexing, needs max swz(784)=791
    __shared__ float4 s_bsB[792];
    __shared__ float s_p[784];
    __shared__ float s_cs[144];
    __shared__ float s_pool[32];

    const int b = blockIdx.x;
    const int tid = threadIdx.x;

    for (int i = tid; i < 784; i += 256) s_p[i] = x[(size_t)b * 784 + i];
    __syncthreads();

    // ----- layer 1: [1,28,28] -> conv+pool -> [4,14,14] (in s_p)
    expand_feat(s_p, 784, s_sil, s_bsA, s_bsB, tid);
    __syncthreads();
    conv_pool_phase<1, 28, 28, 4, 2>(wb1, ws1, s_sil, s_bsA, s_bsB, s_p, tid);
    __syncthreads();

    // ----- layer 2: [4,14,14] -> conv+pool -> [8,7,7] (in s_p)
    expand_feat(s_p, 784, s_sil, s_bsA, s_bsB, tid);
    __syncthreads();
    conv_pool_phase<4, 14, 14, 8, 2>(wb2, ws2, s_sil, s_bsA, s_bsB, s_p, tid);
    __syncthreads();

    // ----- layer 3: [8,7,7] -> conv [16,7,7] (into s_p) -> pool [16,3,3] (s_cs)
    expand_feat(s_p, 392, s_sil, s_bsA, s_bsB, tid);
    __syncthreads();
    conv_phase<8, 7, 7, 16, 4>(wb3, ws3, s_sil, s_bsA, s_bsB, s_p, tid);
    __syncthreads();
    {   // 2x2/2 pool 7x7 -> 3x3, 16 channels = 144 outputs
        for (int i = tid; i < 144; i += 256) {
            int o = i / 9;
            int r = i - o * 9;
            int py = r / 3, qx = r - py * 3;
            const float* src = &s_p[o * 49 + (2 * py) * 7 + 2 * qx];
            s_cs[i] = fmaxf(fmaxf(src[0], src[1]), fmaxf(src[7], src[8]));
        }
    }
    __syncthreads();

    // ----- layer 4 + global-avg + fc (algebraically collapsed via wr)
    if (tid < 144) {
        float v = s_cs[tid];
        s_sil[tid] = silu_f(v);
        float bb[8];
        bspline8(v, bb);
        s_bsA[swz(tid)] = make_float4(bb[0], bb[1], bb[2], bb[3]);
        s_bsB[swz(tid)] = make_float4(bb[4], bb[5], bb[6], bb[7]);
    }
    __syncthreads();
    if (tid < 144) {  // 16 channels x 9 components (silu, 8 bases)
        int c = tid / 9, comp = tid % 9;
        float s = 0.0f;
        for (int p = 0; p < 9; ++p) {
            int idx = c * 9 + p;
            float val;
            if (comp == 0) {
                val = s_sil[idx];
            } else {
                int j = comp - 1;
                val = (j < 4) ? ((const float*)&s_bsA[swz(idx)])[j]
                              : ((const float*)&s_bsB[swz(idx)])[j - 4];
            }
            s += val;
        }
        s_cs[tid] = s;
    }
    __syncthreads();
    if (tid < 32) {
        int o = tid;
        float acc = wr[4608 + o];  // 7 * sum(ws4 * B(0))
        for (int c = 0; c < 16; ++c) {
            acc += wr[o * 16 + c] * s_cs[c * 9 + 0];
#pragma unroll
            for (int j = 0; j < 8; ++j)
                acc += wr[512 + (o * 16 + c) * 8 + j] * s_cs[c * 9 + 1 + j];
        }
        s_pool[o] = acc * (1.0f / 16.0f);
    }
    __syncthreads();
    if (tid < 10) {
        float acc = fcb[tid];
#pragma unroll
        for (int c = 0; c < 32; ++c) acc += fcw[tid * 32 + c] * s_pool[c];
        out[(size_t)b * 10 + tid] = acc;
    }
}

// ---------------------------------------------------------------------------
extern "C" void kernel_launch(void* const* d_in, const int* in_sizes, int n_in,
                              void* d_out, int out_size, void* d_ws, size_t ws_size,
                              hipStream_t stream) {
    const float* x = (const float*)d_in[0];      // [B,1,28,28]
    const float* wb1 = (const float*)d_in[1];    // [4,9]
    const float* ws1 = (const float*)d_in[2];    // [4,9,8]
    const float* wb2 = (const float*)d_in[3];    // [8,36]
    const float* ws2 = (const float*)d_in[4];    // [8,36,8]
    const float* wb3 = (const float*)d_in[5];    // [16,72]
    const float* ws3 = (const float*)d_in[6];    // [16,72,8]
    const float* wb4 = (const float*)d_in[7];    // [32,64]
    const float* ws4 = (const float*)d_in[8];    // [32,64,8]
    const float* fcw = (const float*)d_in[9];    // [10,32]
    const float* fcb = (const float*)d_in[10];   // [10]
    float* out = (float*)d_out;

    const int B = in_sizes[0] / (28 * 28);
    float* wr = (float*)d_ws;  // 4640 floats

    kan4_reduce<<<1, 256, 0, stream>>>(wb4, ws4, wr);
    kan_fused<<<B, 256, 0, stream>>>(x, wb1, ws1, wb2, ws2, wb3, ws3, wr, fcw,
                                     fcb, out);
}